// Round 1
// baseline (204.452 us; speedup 1.0000x reference)
//
#include <hip/hip_runtime.h>

#define NTH 512   // 8 waves; 16 rows/block; grid 512 -> 2 blocks/CU = 16 waves/CU

typedef _Float16 half8 __attribute__((ext_vector_type(8)));
typedef __attribute__((ext_vector_type(4))) float floatx4;

#define LOG2E 1.44269504088896340736f

// DPP add stage; 0x140,0x141,0x4E,0xB1 together = 16-lane sum broadcast
template<int CTRL>
__device__ __forceinline__ float dpp_add(float v) {
    int o = __builtin_amdgcn_update_dpp(0, __float_as_int(v), CTRL, 0xF, 0xF, true);
    return v + __int_as_float(o);
}

#define MFMA16 __builtin_amdgcn_mfma_f32_16x16x32_f16

// ---------------------------------------------------------------------------
// Encoder layer: [16,128] (LDS) @ W[128,128] + bias -> [16,128] (LDS)
// 512 threads: c = tid&127 (out col), g = tid>>7 (row group of 4)
// ---------------------------------------------------------------------------
template<bool RELU>
__device__ __forceinline__ void mlp_layer(const float (*in)[132],
                                          const float* __restrict__ W,
                                          const float* __restrict__ bias,
                                          float (*outl)[132], int c, int g) {
    float acc[4];
    #pragma unroll
    for (int i = 0; i < 4; i++) acc[i] = 0.f;
    for (int k = 0; k < 128; k += 4) {
        float w0 = W[(k + 0) * 128 + c];
        float w1 = W[(k + 1) * 128 + c];
        float w2 = W[(k + 2) * 128 + c];
        float w3 = W[(k + 3) * 128 + c];
        #pragma unroll
        for (int i = 0; i < 4; i++) {
            const float4 xv = *(const float4*)&in[g * 4 + i][k];
            acc[i] = fmaf(xv.x, w0, fmaf(xv.y, w1, fmaf(xv.z, w2, fmaf(xv.w, w3, acc[i]))));
        }
    }
    const float bv = bias[c];
    #pragma unroll
    for (int i = 0; i < 4; i++) {
        float v = acc[i] + bv;
        outl[g * 4 + i][c] = RELU ? fmaxf(v, 0.f) : v;
    }
}

// ---------------------------------------------------------------------------
// Fused encoder + 50-iter GRU (single-pass f16 MFMA) + per-wave decoder.
// 16 rows/block, 8 waves; wave w owns gate cols {g*128 + w*16 + l15}.
// Weights/biases for r,z pre-scaled by log2e (n-gate by 2*log2e) so the
// nonlinearities use raw v_exp_f32 (exp2) with no argument multiply.
// Gate biases are folded into the MFMA accumulator init.
// ---------------------------------------------------------------------------
__global__ __launch_bounds__(NTH, 4)
void gru_fused_kernel(const float* __restrict__ x,
                      const float* __restrict__ ew0, const float* __restrict__ eb0,
                      const float* __restrict__ ew1, const float* __restrict__ eb1,
                      const float* __restrict__ ew2, const float* __restrict__ eb2,
                      const float* __restrict__ w_ih, const float* __restrict__ w_hh,
                      const float* __restrict__ b_ih, const float* __restrict__ b_hh,
                      const float* __restrict__ dw0, const float* __restrict__ db0,
                      const float* __restrict__ dw1, const float* __restrict__ db1,
                      float* __restrict__ out) {
    __shared__ float hA[16][132];                        // encoder staging
    __shared__ float smemB[16 * 132];                    // encoder ping buffer
    __shared__ __align__(16) _Float16 h16[2][16][136];   // f16 h planes (dbuf)
    __shared__ float outb[16][52];

    const int tid  = threadIdx.x;
    const int b0   = blockIdx.x * 16;
    const int lane = tid & 63;
    const int w    = tid >> 6;     // wave 0..7
    const int quad = lane >> 4;
    const int l15  = lane & 15;

    // ---------------- encoder: x -> hA ----------------
    {
        const int c = tid & 127;
        const int g = tid >> 7;    // 0..3, 4 rows each
        float acc[4];
        #pragma unroll
        for (int i = 0; i < 4; i++) acc[i] = 0.f;
        for (int k = 0; k < 256; k += 4) {
            float w0 = ew0[(k + 0) * 128 + c];
            float w1 = ew0[(k + 1) * 128 + c];
            float w2 = ew0[(k + 2) * 128 + c];
            float w3 = ew0[(k + 3) * 128 + c];
            #pragma unroll
            for (int i = 0; i < 4; i++) {
                const float4 xv = *(const float4*)(x + (size_t)(b0 + g * 4 + i) * 256 + k);
                acc[i] = fmaf(xv.x, w0, fmaf(xv.y, w1, fmaf(xv.z, w2, fmaf(xv.w, w3, acc[i]))));
            }
        }
        float bv = eb0[c];
        #pragma unroll
        for (int i = 0; i < 4; i++) hA[g * 4 + i][c] = fmaxf(acc[i] + bv, 0.f);
        __syncthreads();
        mlp_layer<true>(hA, ew1, eb1, (float(*)[132])smemB, c, g);
        __syncthreads();
        mlp_layer<false>((float(*)[132])smemB, ew2, eb2, hA, c, g);
        __syncthreads();
    }

    // ---------------- persistent register weights (f16, pre-scaled) --------
    // wave w covers gate col jc = g*128 + w*16 + l15 (one 16-col tile/wave)
    const int jc = w * 16 + l15;
    half8 wb16[3][4];
    #pragma unroll
    for (int g = 0; g < 3; g++) {
        const float scale = (g == 2) ? 2.f * LOG2E : LOG2E;
        const float* wrow = w_hh + (g * 128 + jc) * 128;
        #pragma unroll
        for (int kt = 0; kt < 4; kt++) {
            const int kb = kt * 32 + quad * 8;
            half8 hv;
            #pragma unroll
            for (int e = 0; e < 8; e++) hv[e] = (_Float16)(wrow[kb + e] * scale);
            wb16[g][kt] = hv;
        }
    }
    half8 dw16[4];
    #pragma unroll
    for (int kt = 0; kt < 4; kt++) {
        half8 hv;
        #pragma unroll
        for (int e = 0; e < 8; e++)
            hv[e] = (_Float16)dw0[(kt * 32 + quad * 8 + e) * 16 + l15];
        dw16[kt] = hv;
    }
    // gate constants (pre-scaled; biases fold into acc init)
    const float wihc0 = w_ih[jc] * LOG2E;
    const float wihc1 = w_ih[128 + jc] * LOG2E;
    const float wihc2 = w_ih[256 + jc] * (2.f * LOG2E);
    const float bs0   = (b_ih[jc] + b_hh[jc]) * LOG2E;
    const float bs1   = (b_ih[128 + jc] + b_hh[128 + jc]) * LOG2E;
    const float bhhn  = b_hh[256 + jc] * (2.f * LOG2E);
    const float bihn  = b_ih[256 + jc] * (2.f * LOG2E);
    const float db0r = db0[l15];
    const float dw1r = dw1[l15];
    const float db1r = db1[0];

    // ---------------- init planes[0] + lane-private fp32 h ----------------
    for (int i = tid; i < 16 * 128; i += NTH) {
        const int b = i >> 7, j = i & 127;
        h16[0][b][j] = (_Float16)hA[b][j];
    }
    if (tid < 16) outb[tid][0] = 0.f;
    float hold[4];   // h at (row quad*4+reg, col jc)
    #pragma unroll
    for (int reg = 0; reg < 4; reg++)
        hold[reg] = hA[quad * 4 + reg][jc];
    __syncthreads();

    // ---------------- 50 iterations: dec(h_t) -> out[t]; gates -> h_{t+1} ---
    for (int t = 0; t <= 49; t++) {
        const int cur = t & 1, nxt = cur ^ 1;

        // A-frags (4 b128; single drain)
        half8 ah[4];
        #pragma unroll
        for (int kt = 0; kt < 4; kt++)
            ah[kt] = *(const half8*)&h16[cur][l15][kt * 32 + quad * 8];

        // decoder (single pass): dacc ready early
        floatx4 dacc = (floatx4){0.f, 0.f, 0.f, 0.f};
        #pragma unroll
        for (int kt = 0; kt < 4; kt++)
            dacc = MFMA16(ah[kt], dw16[kt], dacc, 0, 0, 0);

        // GRU MFMAs (single pass f16): biases pre-loaded into accumulators
        floatx4 acc[3];
        acc[0] = (floatx4){bs0, bs0, bs0, bs0};
        acc[1] = (floatx4){bs1, bs1, bs1, bs1};
        acc[2] = (floatx4){bhhn, bhhn, bhhn, bhhn};
        #pragma unroll
        for (int kt = 0; kt < 4; kt++)
            #pragma unroll
            for (int g = 0; g < 3; g++)
                acc[g] = MFMA16(ah[kt], wb16[g][kt], acc[g], 0, 0, 0);

        // decoder reduce via DPP (16-lane sum within quad-row, broadcast)
        float xp[4];
        #pragma unroll
        for (int reg = 0; reg < 4; reg++) {
            float v = fmaxf(dacc[reg] + db0r, 0.f) * dw1r;
            v = dpp_add<0x140>(v);   // row_mirror
            v = dpp_add<0x141>(v);   // row_half_mirror
            v = dpp_add<0x4E>(v);    // quad_perm xor2
            v = dpp_add<0xB1>(v);    // quad_perm xor1
            xp[reg] = (t == 0) ? 0.f : (v + db1r);
        }
        if (t > 0 && w == 0 && l15 == 0) {
            #pragma unroll
            for (int reg = 0; reg < 4; reg++)
                outb[quad * 4 + reg][t] = xp[reg];
        }

        // gates -> h_{t+1} into planes[nxt]; hold stays fp32
        if (t < 49) {
            #pragma unroll
            for (int reg = 0; reg < 4; reg++) {
                const int b = quad * 4 + reg;
                const float xpv = xp[reg];
                // pre-activations already scaled by log2e (n: 2*log2e)
                float gr = fmaf(xpv, wihc0, acc[0][reg]);
                float gz = fmaf(xpv, wihc1, acc[1][reg]);
                float rg = __builtin_amdgcn_rcpf(1.f + __builtin_amdgcn_exp2f(-gr));
                float zg = __builtin_amdgcn_rcpf(1.f + __builtin_amdgcn_exp2f(-gz));
                float ys = fmaf(rg, acc[2][reg], fmaf(xpv, wihc2, bihn));
                float ng = fmaf(-2.f, __builtin_amdgcn_rcpf(__builtin_amdgcn_exp2f(ys) + 1.f), 1.f);
                const float hn = fmaf(zg, hold[reg] - ng, ng);
                hold[reg] = hn;
                h16[nxt][b][jc] = (_Float16)hn;
            }
        }
        __syncthreads();   // planes[nxt] complete; outb[t] visible
    }

    // coalesced output write: [16 rows][50 cols], col 0 = 0
    for (int e = tid; e < 16 * 50; e += NTH) {
        const int b = e / 50;
        const int t = e - b * 50;
        out[(size_t)b0 * 50 + e] = outb[b][t];
    }
}

// ---------------------------------------------------------------------------
extern "C" void kernel_launch(void* const* d_in, const int* in_sizes, int n_in,
                              void* d_out, int out_size, void* d_ws, size_t ws_size,
                              hipStream_t stream) {
    const float* x   = (const float*)d_in[0];
    const float* ew0 = (const float*)d_in[1];
    const float* eb0 = (const float*)d_in[2];
    const float* ew1 = (const float*)d_in[3];
    const float* eb1 = (const float*)d_in[4];
    const float* ew2 = (const float*)d_in[5];
    const float* eb2 = (const float*)d_in[6];
    const float* wih = (const float*)d_in[7];
    const float* whh = (const float*)d_in[8];
    const float* bih = (const float*)d_in[9];
    const float* bhh = (const float*)d_in[10];
    const float* dw0 = (const float*)d_in[11];
    const float* db0 = (const float*)d_in[12];
    const float* dw1 = (const float*)d_in[13];
    const float* db1 = (const float*)d_in[14];
    float* out = (float*)d_out;

    gru_fused_kernel<<<512, NTH, 0, stream>>>(
        x, ew0, eb0, ew1, eb1, ew2, eb2, wih, whh, bih, bhh,
        dw0, db0, dw1, db1, out);
}

// Round 2
// 200.447 us; speedup vs baseline: 1.0200x; 1.0200x over previous
//
#include <hip/hip_runtime.h>

#define NTH 512   // 8 waves; 16 rows/block; grid 512 -> 2 blocks/CU = 16 waves/CU

typedef _Float16 half8 __attribute__((ext_vector_type(8)));
typedef __attribute__((ext_vector_type(4))) float floatx4;

#define LOG2E 1.44269504088896340736f

// DPP add stage; 0x140,0x141,0x4E,0xB1 together = 16-lane sum broadcast
template<int CTRL>
__device__ __forceinline__ float dpp_add(float v) {
    int o = __builtin_amdgcn_update_dpp(0, __float_as_int(v), CTRL, 0xF, 0xF, true);
    return v + __int_as_float(o);
}

#define MFMA16 __builtin_amdgcn_mfma_f32_16x16x32_f16

// ---------------------------------------------------------------------------
// Encoder layer: [16,128] (LDS) @ W[128,128] + bias -> [16,128] (LDS)
// 512 threads: c = tid&127 (out col), g = tid>>7 (row group of 4)
// ---------------------------------------------------------------------------
template<bool RELU>
__device__ __forceinline__ void mlp_layer(const float (*in)[132],
                                          const float* __restrict__ W,
                                          const float* __restrict__ bias,
                                          float (*outl)[132], int c, int g) {
    float acc[4];
    #pragma unroll
    for (int i = 0; i < 4; i++) acc[i] = 0.f;
    for (int k = 0; k < 128; k += 4) {
        float w0 = W[(k + 0) * 128 + c];
        float w1 = W[(k + 1) * 128 + c];
        float w2 = W[(k + 2) * 128 + c];
        float w3 = W[(k + 3) * 128 + c];
        #pragma unroll
        for (int i = 0; i < 4; i++) {
            const float4 xv = *(const float4*)&in[g * 4 + i][k];
            acc[i] = fmaf(xv.x, w0, fmaf(xv.y, w1, fmaf(xv.z, w2, fmaf(xv.w, w3, acc[i]))));
        }
    }
    const float bv = bias[c];
    #pragma unroll
    for (int i = 0; i < 4; i++) {
        float v = acc[i] + bv;
        outl[g * 4 + i][c] = RELU ? fmaxf(v, 0.f) : v;
    }
}

// ---------------------------------------------------------------------------
// Fused encoder + 50-iter GRU (single-pass f16 MFMA) + decoder via LDS frags.
// 16 rows/block, 8 waves; wave w owns gate col jc = g*128 + w*16 + l15.
// Register-pressure discipline: W_hh persistent in regs (48 VGPR), decoder
// weights streamed per-iter from a 4 KB LDS tile (kills the 16-VGPR dw16
// array that caused R1's scratch spills at the 128-reg/wave budget).
// ---------------------------------------------------------------------------
__global__ __launch_bounds__(NTH, 4)
void gru_fused_kernel(const float* __restrict__ x,
                      const float* __restrict__ ew0, const float* __restrict__ eb0,
                      const float* __restrict__ ew1, const float* __restrict__ eb1,
                      const float* __restrict__ ew2, const float* __restrict__ eb2,
                      const float* __restrict__ w_ih, const float* __restrict__ w_hh,
                      const float* __restrict__ b_ih, const float* __restrict__ b_hh,
                      const float* __restrict__ dw0, const float* __restrict__ db0,
                      const float* __restrict__ dw1, const float* __restrict__ db1,
                      float* __restrict__ out) {
    __shared__ float hA[16][132];                        // encoder staging
    __shared__ float smemB[16 * 132];                    // encoder ping buffer
    __shared__ __align__(16) _Float16 h16[2][16][136];   // f16 h planes (dbuf)
    __shared__ __align__(16) _Float16 dwT[16][136];      // decoder W, transposed
    __shared__ float outb[16][52];

    const int tid  = threadIdx.x;
    const int b0   = blockIdx.x * 16;
    const int lane = tid & 63;
    const int w    = tid >> 6;     // wave 0..7
    const int quad = lane >> 4;
    const int l15  = lane & 15;

    // ---------------- encoder: x -> hA ----------------
    {
        const int c = tid & 127;
        const int g = tid >> 7;    // 0..3, 4 rows each
        float acc[4];
        #pragma unroll
        for (int i = 0; i < 4; i++) acc[i] = 0.f;
        for (int k = 0; k < 256; k += 4) {
            float w0 = ew0[(k + 0) * 128 + c];
            float w1 = ew0[(k + 1) * 128 + c];
            float w2 = ew0[(k + 2) * 128 + c];
            float w3 = ew0[(k + 3) * 128 + c];
            #pragma unroll
            for (int i = 0; i < 4; i++) {
                const float4 xv = *(const float4*)(x + (size_t)(b0 + g * 4 + i) * 256 + k);
                acc[i] = fmaf(xv.x, w0, fmaf(xv.y, w1, fmaf(xv.z, w2, fmaf(xv.w, w3, acc[i]))));
            }
        }
        float bv = eb0[c];
        #pragma unroll
        for (int i = 0; i < 4; i++) hA[g * 4 + i][c] = fmaxf(acc[i] + bv, 0.f);
        __syncthreads();
        mlp_layer<true>(hA, ew1, eb1, (float(*)[132])smemB, c, g);
        __syncthreads();
        mlp_layer<false>((float(*)[132])smemB, ew2, eb2, hA, c, g);
        __syncthreads();
    }

    // ---------------- persistent register weights (f16, pre-scaled) --------
    // wave w covers gate col jc = g*128 + w*16 + l15 (one 16-col tile/wave)
    const int jc = w * 16 + l15;
    half8 wb16[3][4];
    #pragma unroll
    for (int g = 0; g < 3; g++) {
        const float scale = (g == 2) ? 2.f * LOG2E : LOG2E;
        const float* wrow = w_hh + (g * 128 + jc) * 128;
        #pragma unroll
        for (int kt = 0; kt < 4; kt++) {
            const int kb = kt * 32 + quad * 8;
            half8 hv;
            #pragma unroll
            for (int e = 0; e < 8; e++) hv[e] = (_Float16)(wrow[kb + e] * scale);
            wb16[g][kt] = hv;
        }
    }
    // gate constants (pre-scaled; biases fold into acc init)
    const float wihc0 = w_ih[jc] * LOG2E;
    const float wihc1 = w_ih[128 + jc] * LOG2E;
    const float wihc2 = w_ih[256 + jc] * (2.f * LOG2E);
    const float bs0   = (b_ih[jc] + b_hh[jc]) * LOG2E;
    const float bs1   = (b_ih[128 + jc] + b_hh[128 + jc]) * LOG2E;
    const float bhhn  = b_hh[256 + jc] * (2.f * LOG2E);
    const float bihn  = b_ih[256 + jc] * (2.f * LOG2E);
    const float db0r = db0[l15];
    const float dw1r = dw1[l15];
    const float db1r = db1[0];

    // ---------------- init planes[0], dwT, lane-private fp32 h -------------
    for (int i = tid; i < 16 * 128; i += NTH) {
        const int b = i >> 7, j = i & 127;
        h16[0][b][j] = (_Float16)hA[b][j];
    }
    // decoder weights transposed: dwT[c][k] = dw0[k][c], c<16, k<128
    for (int i = tid; i < 16 * 128; i += NTH) {
        const int k = i >> 4, c = i & 15;
        dwT[c][k] = (_Float16)dw0[k * 16 + c];
    }
    if (tid < 16) outb[tid][0] = 0.f;
    float hold[4];   // h at (row quad*4+reg, col jc)
    #pragma unroll
    for (int reg = 0; reg < 4; reg++)
        hold[reg] = hA[quad * 4 + reg][jc];
    __syncthreads();

    // ---------------- 50 iterations: dec(h_t) -> out[t]; gates -> h_{t+1} ---
    for (int t = 0; t <= 49; t++) {
        const int cur = t & 1, nxt = cur ^ 1;

        // MFMAs, interleaved per-kt (short fragment liveness):
        // decoder B-frags come from LDS each iter (no persistent dw16 regs)
        floatx4 dacc = (floatx4){0.f, 0.f, 0.f, 0.f};
        floatx4 acc[3];
        acc[0] = (floatx4){bs0, bs0, bs0, bs0};
        acc[1] = (floatx4){bs1, bs1, bs1, bs1};
        acc[2] = (floatx4){bhhn, bhhn, bhhn, bhhn};
        #pragma unroll
        for (int kt = 0; kt < 4; kt++) {
            const int kb = kt * 32 + quad * 8;
            const half8 ahk = *(const half8*)&h16[cur][l15][kb];
            const half8 dwk = *(const half8*)&dwT[l15][kb];
            dacc = MFMA16(ahk, dwk, dacc, 0, 0, 0);
            acc[0] = MFMA16(ahk, wb16[0][kt], acc[0], 0, 0, 0);
            acc[1] = MFMA16(ahk, wb16[1][kt], acc[1], 0, 0, 0);
            acc[2] = MFMA16(ahk, wb16[2][kt], acc[2], 0, 0, 0);
        }

        // decoder reduce via DPP (16-lane sum within quad-row, broadcast)
        float xp[4];
        #pragma unroll
        for (int reg = 0; reg < 4; reg++) {
            float v = fmaxf(dacc[reg] + db0r, 0.f) * dw1r;
            v = dpp_add<0x140>(v);   // row_mirror
            v = dpp_add<0x141>(v);   // row_half_mirror
            v = dpp_add<0x4E>(v);    // quad_perm xor2
            v = dpp_add<0xB1>(v);    // quad_perm xor1
            xp[reg] = (t == 0) ? 0.f : (v + db1r);
        }
        if (t > 0 && w == 0 && l15 == 0) {
            #pragma unroll
            for (int reg = 0; reg < 4; reg++)
                outb[quad * 4 + reg][t] = xp[reg];
        }

        // gates -> h_{t+1} into planes[nxt]; hold stays fp32
        if (t < 49) {
            #pragma unroll
            for (int reg = 0; reg < 4; reg++) {
                const int b = quad * 4 + reg;
                const float xpv = xp[reg];
                // pre-activations already scaled by log2e (n: 2*log2e)
                float gr = fmaf(xpv, wihc0, acc[0][reg]);
                float gz = fmaf(xpv, wihc1, acc[1][reg]);
                float rg = __builtin_amdgcn_rcpf(1.f + __builtin_amdgcn_exp2f(-gr));
                float zg = __builtin_amdgcn_rcpf(1.f + __builtin_amdgcn_exp2f(-gz));
                float ys = fmaf(rg, acc[2][reg], fmaf(xpv, wihc2, bihn));
                float ng = fmaf(-2.f, __builtin_amdgcn_rcpf(__builtin_amdgcn_exp2f(ys) + 1.f), 1.f);
                const float hn = fmaf(zg, hold[reg] - ng, ng);
                hold[reg] = hn;
                h16[nxt][b][jc] = (_Float16)hn;
            }
        }
        __syncthreads();   // planes[nxt] complete; outb[t] visible
    }

    // coalesced output write: [16 rows][50 cols], col 0 = 0
    for (int e = tid; e < 16 * 50; e += NTH) {
        const int b = e / 50;
        const int t = e - b * 50;
        out[(size_t)b0 * 50 + e] = outb[b][t];
    }
}

// ---------------------------------------------------------------------------
extern "C" void kernel_launch(void* const* d_in, const int* in_sizes, int n_in,
                              void* d_out, int out_size, void* d_ws, size_t ws_size,
                              hipStream_t stream) {
    const float* x   = (const float*)d_in[0];
    const float* ew0 = (const float*)d_in[1];
    const float* eb0 = (const float*)d_in[2];
    const float* ew1 = (const float*)d_in[3];
    const float* eb1 = (const float*)d_in[4];
    const float* ew2 = (const float*)d_in[5];
    const float* eb2 = (const float*)d_in[6];
    const float* wih = (const float*)d_in[7];
    const float* whh = (const float*)d_in[8];
    const float* bih = (const float*)d_in[9];
    const float* bhh = (const float*)d_in[10];
    const float* dw0 = (const float*)d_in[11];
    const float* db0 = (const float*)d_in[12];
    const float* dw1 = (const float*)d_in[13];
    const float* db1 = (const float*)d_in[14];
    float* out = (float*)d_out;

    gru_fused_kernel<<<512, NTH, 0, stream>>>(
        x, ew0, eb0, ew1, eb1, ew2, eb2, wih, whh, bih, bhh,
        dw0, db0, dw1, db1, out);
}